// Round 3
// baseline (158.942 us; speedup 1.0000x reference)
//
#include <hip/hip_runtime.h>

// Geometric product in G(3,0,0), short-lex blade order:
//   [0]=1, [1]=e1, [2]=e2, [3]=e3, [4]=e12, [5]=e13, [6]=e23, [7]=e123
// Cayley tensor is fixed ±1 sparse; 64 FMAs per multivector (hardcoded).
// Memory-bound. R1: 73.8 us, FETCH 134 MB (L3 holds half the inputs),
// WRITE 134 MB. This round: nontemporal (nt) stores so output doesn't evict
// inputs from the 256 MiB Infinity Cache + 2 MVs/thread for more MLP.
// Use native ext_vector_type — __builtin_nontemporal_store rejects
// HIP_vector_type structs.

typedef float f4 __attribute__((ext_vector_type(4)));

__device__ __forceinline__ void gp8(const f4& A, const f4& Ah,
                                    const f4& B, const f4& Bh,
                                    f4& ol, f4& oh)
{
    float a0 = A.x, a1 = A.y, a2 = A.z, a3 = A.w;
    float a4 = Ah.x, a5 = Ah.y, a6 = Ah.z, a7 = Ah.w;
    float b0 = B.x, b1 = B.y, b2 = B.z, b3 = B.w;
    float b4 = Bh.x, b5 = Bh.y, b6 = Bh.z, b7 = Bh.w;

    ol.x = a0*b0 + a1*b1 + a2*b2 + a3*b3 - a4*b4 - a5*b5 - a6*b6 - a7*b7; // 1
    ol.y = a0*b1 + a1*b0 - a2*b4 + a4*b2 - a3*b5 + a5*b3 - a6*b7 - a7*b6; // e1
    ol.z = a0*b2 + a2*b0 + a1*b4 - a4*b1 - a3*b6 + a6*b3 + a5*b7 + a7*b5; // e2
    ol.w = a0*b3 + a3*b0 + a1*b5 - a5*b1 + a2*b6 - a6*b2 - a4*b7 - a7*b4; // e3
    oh.x = a0*b4 + a4*b0 + a1*b2 - a2*b1 - a5*b6 + a6*b5 + a3*b7 + a7*b3; // e12
    oh.y = a0*b5 + a5*b0 + a1*b3 - a3*b1 + a4*b6 - a6*b4 - a2*b7 - a7*b2; // e13
    oh.z = a0*b6 + a6*b0 + a2*b3 - a3*b2 - a4*b5 + a5*b4 + a1*b7 + a7*b1; // e23
    oh.w = a0*b7 + a7*b0 + a1*b6 + a6*b1 - a2*b5 - a5*b2 + a3*b4 + a4*b3; // e123
}

__global__ __launch_bounds__(256) void gp3_kernel(const f4* __restrict__ a,
                                                  const f4* __restrict__ b,
                                                  f4* __restrict__ out,
                                                  int n_mv)
{
    int t = blockIdx.x * blockDim.x + threadIdx.x;
    int mv0 = 2 * t;            // this thread handles MVs mv0, mv0+1
    if (mv0 >= n_mv) return;

    // Issue all 8 loads up front (MLP), then compute, then stream stores.
    f4 al0 = a[2 * mv0];
    f4 ah0 = a[2 * mv0 + 1];
    f4 bl0 = b[2 * mv0];
    f4 bh0 = b[2 * mv0 + 1];

    bool two = (mv0 + 1) < n_mv;
    int mv1 = two ? (mv0 + 1) : mv0;
    f4 al1 = a[2 * mv1];
    f4 ah1 = a[2 * mv1 + 1];
    f4 bl1 = b[2 * mv1];
    f4 bh1 = b[2 * mv1 + 1];

    f4 ol0, oh0, ol1, oh1;
    gp8(al0, ah0, bl0, bh0, ol0, oh0);
    gp8(al1, ah1, bl1, bh1, ol1, oh1);

    __builtin_nontemporal_store(ol0, &out[2 * mv0]);
    __builtin_nontemporal_store(oh0, &out[2 * mv0 + 1]);
    if (two) {
        __builtin_nontemporal_store(ol1, &out[2 * mv1]);
        __builtin_nontemporal_store(oh1, &out[2 * mv1 + 1]);
    }
}

extern "C" void kernel_launch(void* const* d_in, const int* in_sizes, int n_in,
                              void* d_out, int out_size, void* d_ws, size_t ws_size,
                              hipStream_t stream) {
    const f4* a = (const f4*)d_in[0];
    const f4* b = (const f4*)d_in[1];
    // d_in[2] is the cayley tensor [8,8,8] — fixed for METRIC=[1,1,1], hardcoded.
    f4* out = (f4*)d_out;

    int n_mv = in_sizes[0] / 8;
    int n_threads = (n_mv + 1) / 2;
    int block = 256;
    int grid = (n_threads + block - 1) / block;
    gp3_kernel<<<grid, block, 0, stream>>>(a, b, out, n_mv);
}

// Round 4
// 64.165 us; speedup vs baseline: 2.4771x; 2.4771x over previous
//
#include <hip/hip_runtime.h>

// Geometric product in G(3,0,0), short-lex blade order:
//   [0]=1, [1]=e1, [2]=e2, [3]=e3, [4]=e12, [5]=e13, [6]=e23, [7]=e123
// Cayley tensor fixed ±1 sparse; 64 FMAs/MV hardcoded. Memory-bound.
// R1 (1 MV/thread, plain stores): 73.8 us, FETCH 134 MB, WRITE 134 MB.
// R3 (2 MV/thread + nt): 159 us — uncoalesced lanes (64B stride) + nt
//   write amplification (WRITE 189 MB). Reverted the 2/thread split.
// R4: 1 MV/thread (fully coalesced: wave = 1 KiB contiguous per instr)
//   + nt stores. Inputs are exactly 256 MiB = L3 capacity; keeping the
//   output out of L3 should make inputs ~fully L3-resident.

typedef float f4 __attribute__((ext_vector_type(4)));

__global__ __launch_bounds__(256) void gp3_kernel(const f4* __restrict__ a,
                                                  const f4* __restrict__ b,
                                                  f4* __restrict__ out,
                                                  int n_mv)
{
    int idx = blockIdx.x * blockDim.x + threadIdx.x;
    if (idx >= n_mv) return;

    f4 al = a[2 * idx];
    f4 ah = a[2 * idx + 1];
    f4 bl = b[2 * idx];
    f4 bh = b[2 * idx + 1];

    float a0 = al.x, a1 = al.y, a2 = al.z, a3 = al.w;
    float a4 = ah.x, a5 = ah.y, a6 = ah.z, a7 = ah.w;
    float b0 = bl.x, b1 = bl.y, b2 = bl.z, b3 = bl.w;
    float b4 = bh.x, b5 = bh.y, b6 = bh.z, b7 = bh.w;

    f4 ol, oh;
    ol.x = a0*b0 + a1*b1 + a2*b2 + a3*b3 - a4*b4 - a5*b5 - a6*b6 - a7*b7; // 1
    ol.y = a0*b1 + a1*b0 - a2*b4 + a4*b2 - a3*b5 + a5*b3 - a6*b7 - a7*b6; // e1
    ol.z = a0*b2 + a2*b0 + a1*b4 - a4*b1 - a3*b6 + a6*b3 + a5*b7 + a7*b5; // e2
    ol.w = a0*b3 + a3*b0 + a1*b5 - a5*b1 + a2*b6 - a6*b2 - a4*b7 - a7*b4; // e3
    oh.x = a0*b4 + a4*b0 + a1*b2 - a2*b1 - a5*b6 + a6*b5 + a3*b7 + a7*b3; // e12
    oh.y = a0*b5 + a5*b0 + a1*b3 - a3*b1 + a4*b6 - a6*b4 - a2*b7 - a7*b2; // e13
    oh.z = a0*b6 + a6*b0 + a2*b3 - a3*b2 - a4*b5 + a5*b4 + a1*b7 + a7*b1; // e23
    oh.w = a0*b7 + a7*b0 + a1*b6 + a6*b1 - a2*b5 - a5*b2 + a3*b4 + a4*b3; // e123

    __builtin_nontemporal_store(ol, &out[2 * idx]);
    __builtin_nontemporal_store(oh, &out[2 * idx + 1]);
}

extern "C" void kernel_launch(void* const* d_in, const int* in_sizes, int n_in,
                              void* d_out, int out_size, void* d_ws, size_t ws_size,
                              hipStream_t stream) {
    const f4* a = (const f4*)d_in[0];
    const f4* b = (const f4*)d_in[1];
    // d_in[2] is the cayley tensor [8,8,8] — fixed for METRIC=[1,1,1], hardcoded.
    f4* out = (f4*)d_out;

    int n_mv = in_sizes[0] / 8;
    int block = 256;
    int grid = (n_mv + block - 1) / block;
    gp3_kernel<<<grid, block, 0, stream>>>(a, b, out, n_mv);
}